// Round 3
// baseline (393.027 us; speedup 1.0000x reference)
//
#include <hip/hip_runtime.h>
#include <hip/hip_bf16.h>

// Problem constants (setup_inputs: B=16, L=4096, D=1024)
constexpr int B = 16;
constexpr int L = 4096;
constexpr int D = 1024;
constexpr int P = (L - 2) / 2;   // 2047 output positions per batch
constexpr int PSLOT = 2048;      // padded position slots per batch in ws

// ---------------- Kernel 1: gate computation ----------------
// Reads ONLY odd rows (mid). Block = 256 threads = 4 waves, handles 16
// consecutive position slots. Within a wave, lane group g = lane>>4 owns one
// position; the 16 lanes of a group cover the 1024-float row as 16 float4s
// per lane (f4 = lane16 + 16k, coalesced 256B segments per group).
// 16 independent global loads per thread = 256 B in flight per lane.
// G (8 KB) is read from global and stays L1-hot.
__global__ __launch_bounds__(256) void gates_kernel(
    const float* __restrict__ X, const float* __restrict__ G,
    const float* __restrict__ Gb, float2* __restrict__ gates) {
  const int t    = threadIdx.x;
  const int wave = t >> 6;
  const int lane = t & 63;
  const int grp  = lane >> 4;
  const int l16  = lane & 15;

  const int b     = blockIdx.x >> 7;            // 128 blocks per batch
  const int pbase = (blockIdx.x & 127) * 16;
  const int p     = pbase + wave * 4 + grp;     // 0..2047 (slot; 2047 unused downstream)

  // mid row index 2p+1 <= 4095: always in-bounds, even for slot p=2047.
  const float4* m4 = (const float4*)(X + ((size_t)b * L + (2 * p + 1)) * D);
  const float4* g4 = (const float4*)G;

  float4 mbuf[16];
  #pragma unroll
  for (int k = 0; k < 16; ++k) mbuf[k] = m4[l16 + 16 * k];

  float s0 = 0.f, s1 = 0.f;
  #pragma unroll
  for (int k = 0; k < 16; ++k) {
    const int f4 = l16 + 16 * k;
    const float4 ga = g4[2 * f4];       // (G[c][0],G[c][1],G[c+1][0],G[c+1][1]), c=4*f4
    const float4 gb = g4[2 * f4 + 1];
    const float4 m  = mbuf[k];
    s0 += m.x * ga.x + m.y * ga.z + m.z * gb.x + m.w * gb.z;
    s1 += m.x * ga.y + m.y * ga.w + m.z * gb.y + m.w * gb.w;
  }

  // Reduce within each 16-lane group (4 steps).
  #pragma unroll
  for (int off = 1; off < 16; off <<= 1) {
    s0 += __shfl_xor(s0, off, 16);
    s1 += __shfl_xor(s1, off, 16);
  }

  if (l16 == 0) {
    const float t0 = s0 + Gb[0];
    const float t1 = s1 + Gb[1];
    const float mx = fmaxf(t0, t1);
    const float e0 = __expf(t0 - mx);
    const float e1 = __expf(t1 - mx);
    const float inv = 1.0f / (e0 + e1);
    gates[b * PSLOT + p] = make_float2(e0 * inv, e1 * inv);
  }
}

// ---------------- Kernel 2: blend ----------------
// Reads ONLY even rows + the tiny gate array. One wave per chain of 4
// consecutive positions; lane owns float4 indices {64j + lane}. All 20 row
// loads (4 lf + 16 rt) are independent -> 320 B in flight per lane. The
// right row of position i is reused in registers as the left row of i+1.
// No reductions, no barriers.
__global__ __launch_bounds__(256) void blend_kernel(
    const float* __restrict__ X, const float2* __restrict__ gates,
    float* __restrict__ out) {
  const int gtid = blockIdx.x * 256 + threadIdx.x;
  const int wid  = gtid >> 6;          // 0..8191
  const int lane = gtid & 63;
  const int b    = wid >> 9;           // 512 chains per batch
  const int c    = wid & 511;
  const int p0   = c * 4;              // first position of chain (0..2044)

  const float* xb = X + (size_t)b * L * D;

  float4 lf[4];
  {
    const float4* lrow = (const float4*)(xb + (size_t)(2 * p0) * D);
    #pragma unroll
    for (int j = 0; j < 4; ++j) lf[j] = lrow[64 * j + lane];
  }

  float4 rt[4][4];
  #pragma unroll
  for (int i = 0; i < 4; ++i) {
    // Clamp keeps the very last chain's row 4096 in-bounds (value unused).
    const int row = min(2 * p0 + 2 * i + 2, L - 1);
    const float4* rrow = (const float4*)(xb + (size_t)row * D);
    #pragma unroll
    for (int j = 0; j < 4; ++j) rt[i][j] = rrow[64 * j + lane];
  }

  float2 g[4];
  #pragma unroll
  for (int i = 0; i < 4; ++i) g[i] = gates[b * PSLOT + p0 + i];

  float* ob = out + (size_t)b * P * D;
  #pragma unroll
  for (int i = 0; i < 4; ++i) {
    const int p = p0 + i;
    if (p < P) {
      float4* orow = (float4*)(ob + (size_t)p * D);
      #pragma unroll
      for (int j = 0; j < 4; ++j) {
        float4 r;
        r.x = lf[j].x * g[i].x + rt[i][j].x * g[i].y;
        r.y = lf[j].y * g[i].x + rt[i][j].y * g[i].y;
        r.z = lf[j].z * g[i].x + rt[i][j].z * g[i].y;
        r.w = lf[j].w * g[i].x + rt[i][j].w * g[i].y;
        orow[64 * j + lane] = r;
      }
    }
    #pragma unroll
    for (int j = 0; j < 4; ++j) lf[j] = rt[i][j];
  }
}

extern "C" void kernel_launch(void* const* d_in, const int* in_sizes, int n_in,
                              void* d_out, int out_size, void* d_ws, size_t ws_size,
                              hipStream_t stream) {
  const float* X  = (const float*)d_in[0];
  const float* G  = (const float*)d_in[1];
  const float* Gb = (const float*)d_in[2];
  float* out = (float*)d_out;
  float2* gates = (float2*)d_ws;       // needs 16*2048*8 B = 256 KB of ws

  // Kernel 1: 16 batches * 128 blocks (16 positions each) = 2048 blocks.
  gates_kernel<<<dim3(B * 128), dim3(256), 0, stream>>>(X, G, Gb, gates);
  // Kernel 2: 16 batches * 512 chains = 8192 waves = 2048 blocks.
  blend_kernel<<<dim3(B * 512 / 4), dim3(256), 0, stream>>>(X, gates, out);
}